// Round 5
// baseline (900.546 us; speedup 1.0000x reference)
//
#include <hip/hip_runtime.h>
#include <hip/hip_bf16.h>
#include <stdint.h>
#include <stddef.h>

typedef __attribute__((ext_vector_type(8))) short short8;
typedef __attribute__((ext_vector_type(4))) float f32x4;

#define NB 2048
#define HD 512
#define SD 256

__device__ __forceinline__ short f2bf(float x) {
  __hip_bfloat16 h = __float2bfloat16(x);
  return *reinterpret_cast<short*>(&h);
}

__device__ __forceinline__ float fast_tanh(float x) {
  x = fminf(fmaxf(x, -15.f), 15.f);
  float e = __expf(2.f * x);
  return __fdividef(e - 1.f, e + 1.f);
}

// ---- Wtb[kb][j][kk] = bf16(W[kb*32+kk][j]) : k-blocked transposed layout ----
__global__ __launch_bounds__(256) void wconv_kernel(const float* __restrict__ W,
                                                    short* __restrict__ Wtb) {
  __shared__ float tile[32][33];
  const int bx = blockIdx.x;
  const int tk0 = (bx & 15) * 32;
  const int tj0 = (bx >> 4) * 32;
  const int lx = threadIdx.x & 31;
  const int ly = threadIdx.x >> 5;
  for (int r = 0; r < 4; ++r) {
    int yy = ly + r * 8;
    tile[yy][lx] = W[(size_t)(tk0 + yy) * HD + tj0 + lx];
  }
  __syncthreads();
  const int kb = tk0 >> 5;
  for (int r = 0; r < 4; ++r) {
    int yy = ly + r * 8;
    Wtb[(size_t)kb * (HD * 32) + (size_t)(tj0 + yy) * 32 + lx] = f2bf(tile[lx][yy]);
  }
}

// ---- alignment[n][s] = sum_j tanh( sum_k hs[n,k,s]*W[k,j] + b[j] ) * c[j] ----
// Block = 4 waves on the SAME 64-s chunk, each owning a 128-j slice.
// No LDS / no barriers in the k-loop. Software-pipelined depth-1 register
// prefetch of the HBM-latency-critical A loads:
//   per step: issue wf(kt) FIRST, then raw-A(kt+1); pack previous raw-A;
//   MFMA waits vmcnt(32) -> the 32 A-prefetch loads stay in flight across
//   the MFMA cluster (counted wait, not a drain).
__global__ void __launch_bounds__(256, 2)
align_kernel(const float* __restrict__ hs, const short* __restrict__ Wtb,
             const float* __restrict__ bias, const float* __restrict__ ctx,
             float* __restrict__ align_out)
{
  __shared__ float abuf[64];

  const int tid = threadIdx.x;
  const int n = blockIdx.x >> 2;
  const int s0 = (blockIdx.x & 3) * 64;
  const int lane = tid & 63;
  const int wid = tid >> 6;
  const int l15 = lane & 15;
  const int lg = lane >> 4;
  const int jb = wid * 128;

  if (tid < 64) abuf[tid] = 0.f;
  __syncthreads();

  // A (B-operand of mfma): lane needs hs[n][k = kt*32 + lg*8 + e][s0 + i*16 + l15]
  const float* hsA = hs + (size_t)n * (HD * SD) + s0 + l15 + (size_t)(lg * 8) * SD;
  // W (A-operand of mfma): lane needs Wtb[kt][j = jb + p*16 + l15][lg*8 + e]
  const short* wbase = Wtb + (size_t)(jb + l15) * 32 + lg * 8;

  f32x4 acc[4][8];
  #pragma unroll
  for (int i = 0; i < 4; ++i)
    #pragma unroll
    for (int p = 0; p < 8; ++p)
      acc[i][p] = (f32x4){0.f, 0.f, 0.f, 0.f};

  // prologue: issue raw-A loads for kt = 0
  float ra[32];
  #pragma unroll
  for (int i = 0; i < 4; ++i)
    #pragma unroll
    for (int e = 0; e < 8; ++e)
      ra[i * 8 + e] = hsA[(size_t)e * SD + i * 16];

  #pragma unroll 2
  for (int kt = 0; kt < 16; ++kt) {
    // 1) W fragments for THIS step: 8 x dwordx4 (L2-resident, issued first so
    //    the MFMA wait below is vmcnt(32), leaving the A-prefetch in flight)
    short8 wf[8];
    const short* wk = wbase + (size_t)kt * (HD * 32);
    #pragma unroll
    for (int p = 0; p < 8; ++p)
      wf[p] = *(const short8*)(wk + p * (16 * 32));

    // 2) issue raw-A loads for NEXT step (HBM-latency-critical prefetch)
    float rb[32];
    if (kt < 15) {
      const float* an = hsA + (size_t)((kt + 1) * 32) * SD;
      #pragma unroll
      for (int i = 0; i < 4; ++i)
        #pragma unroll
        for (int e = 0; e < 8; ++e)
          rb[i * 8 + e] = an[(size_t)e * SD + i * 16];
    }

    // 3) pack previous raw-A (loads retired one full step ago) -> af
    short8 af[4];
    #pragma unroll
    for (int i = 0; i < 4; ++i) {
      short8 pk;
      #pragma unroll
      for (int e = 0; e < 8; ++e) pk[e] = f2bf(ra[i * 8 + e]);
      af[i] = pk;
    }

    // 4) 32 MFMAs: D[j][s] += Wfrag(16j x 32k) * Afrag(32k x 16s)
    #pragma unroll
    for (int i = 0; i < 4; ++i)
      #pragma unroll
      for (int p = 0; p < 8; ++p)
        acc[i][p] = __builtin_amdgcn_mfma_f32_16x16x32_bf16(wf[p], af[i], acc[i][p], 0, 0, 0);

    // 5) rotate prefetch buffer (vanishes under unroll-2 renaming)
    if (kt < 15) {
      #pragma unroll
      for (int e = 0; e < 32; ++e) ra[e] = rb[e];
    }
  }

  // epilogue: D rows = j (lg*4 + r per fragment), cols = s (l15).
  // tanh + *c, in-lane sum over this wave's 128 j, 2 shuffles over lg groups,
  // then one LDS atomic reduction across the 4 j-slice waves.
  float part[4] = {0.f, 0.f, 0.f, 0.f};
  #pragma unroll
  for (int p = 0; p < 8; ++p) {
    const int j = jb + p * 16 + lg * 4;
    f32x4 bv = *(const f32x4*)(bias + j);
    f32x4 cv = *(const f32x4*)(ctx + j);
    #pragma unroll
    for (int i = 0; i < 4; ++i)
      #pragma unroll
      for (int r = 0; r < 4; ++r)
        part[i] += fast_tanh(acc[i][p][r] + bv[r]) * cv[r];
  }
  #pragma unroll
  for (int i = 0; i < 4; ++i) {
    part[i] += __shfl_xor(part[i], 16);
    part[i] += __shfl_xor(part[i], 32);
  }
  if (lg == 0) {
    #pragma unroll
    for (int i = 0; i < 4; ++i)
      atomicAdd(&abuf[i * 16 + l15], part[i]);
  }
  __syncthreads();
  if (tid < 64) align_out[(size_t)n * SD + s0 + tid] = abuf[tid];
}

// ---- softmax over s + context[n,h] = sum_s attn[s]*hs[n,h,s] ----
__global__ __launch_bounds__(256) void ctx_kernel(const float* __restrict__ hs,
                                                  const float* __restrict__ align_in,
                                                  float* __restrict__ out)
{
  __shared__ __align__(16) float attn_s[256];
  __shared__ float red[8];
  const int n = blockIdx.x;
  const int t = threadIdx.x;
  const int lane = t & 63, wid = t >> 6;

  float a = align_in[(size_t)n * 256 + t];
  float m = a;
  #pragma unroll
  for (int off = 32; off; off >>= 1) m = fmaxf(m, __shfl_xor(m, off));
  if (lane == 0) red[wid] = m;
  __syncthreads();
  m = fmaxf(fmaxf(red[0], red[1]), fmaxf(red[2], red[3]));
  float e = __expf(a - m);
  float s = e;
  #pragma unroll
  for (int off = 32; off; off >>= 1) s += __shfl_xor(s, off);
  if (lane == 0) red[4 + wid] = s;
  __syncthreads();
  s = red[4] + red[5] + red[6] + red[7];
  attn_s[t] = e / s;
  __syncthreads();

  const int grp = t & 7;      // s-chunk of 32
  const int hrow = t >> 3;    // 0..31
  float av[32];
  #pragma unroll
  for (int u = 0; u < 8; ++u) {
    float4 v = *(const float4*)&attn_s[grp * 32 + u * 4];
    av[4*u+0] = v.x; av[4*u+1] = v.y; av[4*u+2] = v.z; av[4*u+3] = v.w;
  }
  const float* hb = hs + (size_t)n * (HD * SD) + grp * 32;
  for (int it = 0; it < 16; ++it) {
    const int h = it * 32 + hrow;
    const float4* p = (const float4*)(hb + (size_t)h * SD);
    float acc = 0.f;
    #pragma unroll
    for (int u = 0; u < 8; ++u) {
      float4 v = p[u];
      acc += av[4*u+0]*v.x + av[4*u+1]*v.y + av[4*u+2]*v.z + av[4*u+3]*v.w;
    }
    acc += __shfl_xor(acc, 1);
    acc += __shfl_xor(acc, 2);
    acc += __shfl_xor(acc, 4);
    if (grp == 0) out[(size_t)n * HD + h] = acc;
  }
}

extern "C" void kernel_launch(void* const* d_in, const int* in_sizes, int n_in,
                              void* d_out, int out_size, void* d_ws, size_t ws_size,
                              hipStream_t stream) {
  (void)in_sizes; (void)n_in; (void)out_size; (void)ws_size;
  const float* hs = (const float*)d_in[0];
  const float* W  = (const float*)d_in[1];
  const float* b  = (const float*)d_in[2];
  const float* c  = (const float*)d_in[3];
  float* out = (float*)d_out;

  float* align_ws = (float*)d_ws;                                  // 2 MB
  short* Wtb = (short*)((char*)d_ws + (size_t)NB * SD * 4);        // 512 KB

  wconv_kernel<<<256, 256, 0, stream>>>(W, Wtb);
  align_kernel<<<NB * 4, 256, 0, stream>>>(hs, Wtb, b, c, align_ws);
  ctx_kernel<<<NB, 256, 0, stream>>>(hs, align_ws, out);
}